// Round 4
// baseline (2009.648 us; speedup 1.0000x reference)
//
#include <hip/hip_runtime.h>
#include <math.h>

// Problem constants
constexpr int BB = 32, NN = 100, CH = 128, NH = 8, NL = 3;
constexpr int NR = BB * NN;          // 3200 node rows
constexpr int ERR = BB * NN * NN;    // 320000 edge rows
constexpr float EPS = 1e-5f;
constexpr int LDST = 132;            // padded LDS row stride (floats)

// ---------------- ws layout (floats) ----------------
constexpr size_t OFF_G     = 0;                       // 409600
constexpr size_t OFF_SI    = OFF_G     + 409600;      // 25600
constexpr size_t OFF_SJ    = OFF_SI    + 25600;       // 25600
constexpr size_t OFF_HE1   = OFF_SJ    + 25600;       // 409600
constexpr size_t OFF_HE2   = OFF_HE1   + 409600;
constexpr size_t OFF_KB    = OFF_HE2   + 409600;
constexpr size_t OFF_VB    = OFF_KB    + 409600;
constexpr size_t OFF_HRAW  = OFF_VB    + 409600;      // raw (pre-BN) h state
constexpr size_t OFF_HSTMP = OFF_HRAW  + 409600;      // 4096
constexpr size_t OFF_HSS   = OFF_HSTMP + 4096;        // 4096
constexpr size_t OFF_WES2  = OFF_HSS   + 4096;        // 1024  (w_es [h][c] * dsc[c])
constexpr size_t OFF_WEC   = OFF_WES2  + 1024;        // 16
constexpr size_t OFF_EWST  = OFF_WEC   + 16;          // 16384 (EwS^T [c][o])
constexpr size_t OFF_EB2   = OFF_EWST  + 16384;       // 128
constexpr size_t OFF_WGT   = OFF_EB2   + 128;         // 3*16384
constexpr size_t OFF_H1T   = OFF_WGT   + 49152;
constexpr size_t OFF_H2T   = OFF_H1T   + 49152;
constexpr size_t OFF_WKT   = OFF_H2T   + 49152;
constexpr size_t OFF_WVT   = OFF_WKT   + 49152;
constexpr size_t OFF_DSC   = OFF_WVT   + 49152;       // 4*128 (dis affine per layer boundary; slot 0 = identity)
constexpr size_t OFF_DSH   = OFF_DSC   + 512;         // 4*128
constexpr size_t OFF_STATS = OFF_DSH   + 512;         // 4096 floats = 2048 DOUBLES (8B aligned)
constexpr size_t OFF_NSC   = OFF_STATS + 4096;        // 3*128 (node BN affine per layer)
constexpr size_t OFF_NSH   = OFF_NSC   + 384;         // 3*128

__device__ __forceinline__ float4 ldg4(const float* p) {
    return *reinterpret_cast<const float4*>(p);
}
__device__ __forceinline__ float get4(const float4& v, int q) {
    return q == 0 ? v.x : q == 1 ? v.y : q == 2 ? v.z : v.w;
}

// stage 64 contiguous rows (64*128 floats) into padded LDS
template<int NT>
__device__ __forceinline__ void stage64(const float* __restrict__ src, float* lds, int t) {
    #pragma unroll
    for (int k = 0; k < 2048 / NT; ++k) {
        int idx4 = t + k * NT;
        int row = idx4 >> 5, c = (idx4 & 31) << 2;
        *reinterpret_cast<float4*>(lds + row * LDST + c) = ldg4(src + (size_t)idx4 * 4);
    }
}

// stage with per-channel affine applied (c4 = t&31 is thread-constant for NT=256)
template<int NT>
__device__ __forceinline__ void stage64_aff(const float* __restrict__ src, float* lds, int t,
                                            float4 sc, float4 sh) {
    #pragma unroll
    for (int k = 0; k < 2048 / NT; ++k) {
        int idx4 = t + k * NT;
        int row = idx4 >> 5, c = (idx4 & 31) << 2;
        float4 v = ldg4(src + (size_t)idx4 * 4);
        v.x = v.x * sc.x + sh.x; v.y = v.y * sc.y + sh.y;
        v.z = v.z * sc.z + sh.z; v.w = v.w * sc.w + sh.w;
        *reinterpret_cast<float4*>(lds + row * LDST + c) = v;
    }
}

// inner GEMM: one lane's row (in LDS) dotted against 32 columns of transposed weight
__device__ __forceinline__ void rowtile_gemm(const float* lds_row, const float* __restrict__ wt,
                                             int obase, float* acc) {
    for (int c = 0; c < CH; c += 4) {
        float4 av = *reinterpret_cast<const float4*>(lds_row + c);
        #pragma unroll
        for (int q = 0; q < 4; ++q) {
            float a = get4(av, q);
            const float* wr = wt + (c + q) * CH + obase;
            #pragma unroll
            for (int k4 = 0; k4 < 8; ++k4) {
                float4 w = ldg4(wr + k4 * 4);
                acc[k4 * 4 + 0] += a * w.x;
                acc[k4 * 4 + 1] += a * w.y;
                acc[k4 * 4 + 2] += a * w.z;
                acc[k4 * 4 + 3] += a * w.w;
            }
        }
    }
}

// ---------------- setup: transpose 15 weight matrices + init block ----------------
// grid 16, block 128. blocks 0..14: sel = bx/3, layer = bx%3. block 15: init stats/affine.
__global__ void setup_k(const float* __restrict__ gat_W, const float* __restrict__ et_Hw1,
                        const float* __restrict__ et_Hw2, const float* __restrict__ mha_in_w,
                        float* __restrict__ wgT, float* __restrict__ h1T, float* __restrict__ h2T,
                        float* __restrict__ wkT, float* __restrict__ wvT,
                        double* stats, float* dsc, float* dsh) {
    int m = blockIdx.x, t = threadIdx.x;
    if (m == 15) {
        #pragma unroll
        for (int k = 0; k < 16; ++k) stats[k * 128 + t] = 0.0;
        dsc[t] = 1.f;  // identity affine for layer-0 dis/h reads
        dsh[t] = 0.f;
        return;
    }
    int layer = m % 3, sel = m / 3;
    const float* src; float* dst;
    if (sel == 0)      { src = gat_W   + layer * 16384;              dst = wgT + layer * 16384; }
    else if (sel == 1) { src = et_Hw1  + layer * 16384;              dst = h1T + layer * 16384; }
    else if (sel == 2) { src = et_Hw2  + layer * 16384;              dst = h2T + layer * 16384; }
    else if (sel == 3) { src = mha_in_w + layer * 49152 + 128 * 128; dst = wkT + layer * 16384; }
    else               { src = mha_in_w + layer * 49152 + 256 * 128; dst = wvT + layer * 16384; }
    for (int o = 0; o < 128; ++o) dst[t * 128 + o] = src[o * 128 + t];
}

// merged fold kernel, grid 136:
//  blocks 0..7:   wes2[h][c] = (sum_d We[h*16+d][c]*a_e[d]) * dscP[c]; wec[h] = sum_c (...)*dshP[c]
//  blocks 8..135: EwS^T[c][o] = Ew[o][c]*dscP[c]; eb2[o] = Eb[o] + sum_c Ew[o][c]*dshP[c]
__global__ void fold_k(const float* __restrict__ We, const float* __restrict__ ga,
                       const float* __restrict__ Ew, const float* __restrict__ Eb,
                       const float* __restrict__ dscP, const float* __restrict__ dshP,
                       float* __restrict__ wes2, float* __restrict__ wec,
                       float* __restrict__ ewsT, float* __restrict__ eb2) {
    __shared__ float red[128];
    int c = threadIdx.x;
    if (blockIdx.x < 8) {
        int h = blockIdx.x;
        float w = 0.f;
        #pragma unroll
        for (int d = 0; d < 16; ++d) w += We[(h * 16 + d) * CH + c] * ga[32 + d];
        wes2[h * CH + c] = w * dscP[c];
        red[c] = w * dshP[c];
        __syncthreads();
        for (int s = 64; s >= 1; s >>= 1) {
            if (c < s) red[c] += red[c + s];
            __syncthreads();
        }
        if (c == 0) wec[h] = red[0];
    } else {
        int o = blockIdx.x - 8;
        float v = Ew[o * CH + c];
        ewsT[c * CH + o] = v * dscP[c];
        red[c] = v * dshP[c];
        __syncthreads();
        for (int s = 64; s >= 1; s >>= 1) {
            if (c < s) red[c] += red[c + s];
            __syncthreads();
        }
        if (c == 0) eb2[o] = Eb[o] + red[0];
    }
}

// ---------------- per-layer kernels ----------------
// P1: g = hn @ W^T; si/sj head dots. grid 50, block 256. hn = hraw*sc+sh applied in staging.
__global__ __launch_bounds__(256, 2) void p1_k(const float* __restrict__ hsrc,
                                               const float* __restrict__ scp, const float* __restrict__ shp,
                                               const float* __restrict__ wgt,
                                               const float* __restrict__ ga,
                                               float* __restrict__ g, float* __restrict__ si,
                                               float* __restrict__ sj) {
    __shared__ float lds[64 * LDST];
    int t = threadIdx.x, tile = blockIdx.x;
    float4 scv = reinterpret_cast<const float4*>(scp)[t & 31];
    float4 shv = reinterpret_cast<const float4*>(shp)[t & 31];
    stage64_aff<256>(hsrc + (size_t)tile * 64 * CH, lds, t, scv, shv);
    __syncthreads();
    int lane = t & 63;
    int obase = __builtin_amdgcn_readfirstlane((t >> 6) << 5);
    int row = tile * 64 + lane;
    float acc[32];
    #pragma unroll
    for (int k = 0; k < 32; ++k) acc[k] = 0.f;
    rowtile_gemm(lds + lane * LDST, wgt, obase, acc);
    float si0 = 0, si1 = 0, sj0 = 0, sj1 = 0;
    #pragma unroll
    for (int k = 0; k < 16; ++k) {
        si0 += acc[k] * ga[k];       sj0 += acc[k] * ga[16 + k];
        si1 += acc[16 + k] * ga[k];  sj1 += acc[16 + k] * ga[16 + k];
    }
    int h0 = obase >> 4;
    si[row * NH + h0] = si0; si[row * NH + h0 + 1] = si1;
    sj[row * NH + h0] = sj0; sj[row * NH + h0 + 1] = sj1;
    #pragma unroll
    for (int k4 = 0; k4 < 8; ++k4) {
        float4 o4 = {acc[k4 * 4], acc[k4 * 4 + 1], acc[k4 * 4 + 2], acc[k4 * 4 + 3]};
        *reinterpret_cast<float4*>(&g[(size_t)row * CH + obase + k4 * 4]) = o4;
    }
}

// GAT attention + h update, with s_e computed in-block from dis rows (b,i,*).
// grid 3200 (b*100+i), block 128. Thread t: h = t&7, jj = t>>3 (16 j-stripes).
__global__ __launch_bounds__(128) void att_k(const float* __restrict__ dsrc,
                                             const float* __restrict__ wes2, const float* __restrict__ wec,
                                             const float* __restrict__ si, const float* __restrict__ sj,
                                             const int* __restrict__ adj, const float* __restrict__ g,
                                             const float* __restrict__ hsrc,
                                             const float* __restrict__ scp, const float* __restrict__ shp,
                                             float* __restrict__ hraw) {
    __shared__ float es[NN * 8];
    int t = threadIdx.x;
    int bi = blockIdx.x;
    int b = bi / NN;
    int h = t & 7, jj = t >> 3;
    // phase A: se[j][h] = dis_raw[b,i,j,:] . wes2[h][:] + wec[h]; then e = leaky(si+sj+se), mask
    float sev[7];
    #pragma unroll
    for (int it = 0; it < 7; ++it) sev[it] = 0.f;
    const float* drow0 = dsrc + (size_t)bi * NN * CH;
    #pragma unroll 8
    for (int c4 = 0; c4 < 32; ++c4) {
        float4 wv = ldg4(wes2 + h * CH + c4 * 4);
        #pragma unroll
        for (int it = 0; it < 7; ++it) {
            int j = jj + it * 16;
            if (j < NN) {
                float4 dv = ldg4(drow0 + (size_t)j * CH + c4 * 4);
                sev[it] += dv.x * wv.x + dv.y * wv.y + dv.z * wv.z + dv.w * wv.w;
            }
        }
    }
    float siv = si[bi * 8 + h];
    float wcv = wec[h];
    #pragma unroll
    for (int it = 0; it < 7; ++it) {
        int j = jj + it * 16;
        if (j < NN) {
            float e = siv + sj[(b * NN + j) * 8 + h] + sev[it] + wcv;
            e = e >= 0.f ? e : 0.2f * e;
            if (adj[(size_t)bi * NN + j] == 0) e = -INFINITY;
            es[j * 8 + h] = e;
        }
    }
    __syncthreads();
    // phase B: softmax over j per (head)
    int hs = t >> 4, l = t & 15;
    float m = -INFINITY;
    for (int j = l; j < NN; j += 16) m = fmaxf(m, es[j * 8 + hs]);
    #pragma unroll
    for (int o = 8; o >= 1; o >>= 1) m = fmaxf(m, __shfl_xor(m, o, 16));
    float s = 0.f;
    for (int j = l; j < NN; j += 16) {
        float p = __expf(es[j * 8 + hs] - m);
        es[j * 8 + hs] = p;
        s += p;
    }
    #pragma unroll
    for (int o = 8; o >= 1; o >>= 1) s += __shfl_xor(s, o, 16);
    float inv = 1.f / s;
    for (int j = l; j < NN; j += 16) es[j * 8 + hs] *= inv;
    __syncthreads();
    // phase C: h_out = att @ g + residual (residual = normalized previous h)
    int c = t, hc = c >> 4;
    float acc = 0.f;
    for (int j = 0; j < NN; ++j) acc += es[j * 8 + hc] * g[((size_t)b * NN + j) * CH + c];
    float res = hsrc[(size_t)bi * CH + c] * scp[c] + shp[c];
    hraw[(size_t)bi * CH + c] = acc + res;
}

__global__ void hstats_k(const float* __restrict__ hraw, double* nsum, double* nsq) {
    int b = blockIdx.x, c = threadIdx.x;
    float s = 0.f, q = 0.f;
    for (int n = 0; n < NN; ++n) {
        float v = hraw[((size_t)b * NN + n) * CH + c];
        s += v; q += v * v;
    }
    atomicAdd(&nsum[c], (double)s);
    atomicAdd(&nsq[c], (double)q);
}

__global__ void bnfin_k(const double* __restrict__ sum, const double* __restrict__ sq,
                        const float* __restrict__ gg, const float* __restrict__ bb,
                        double cnt, float* sc, float* sh) {
    int c = threadIdx.x;
    double m = sum[c] / cnt, v = sq[c] / cnt - m * m;
    float s = gg[c] * rsqrtf((float)(v + (double)EPS));
    sc[c] = s;
    sh[c] = bb[c] - (float)m * s;
}

// P2: he1/he2/k/(v) projections of normalized h. grid 50*nmat, block 256.
__global__ __launch_bounds__(256, 2) void p2_k(const float* __restrict__ hraw,
                                               const float* __restrict__ scp, const float* __restrict__ shp,
                                               const float* __restrict__ wt0, const float* __restrict__ wt1,
                                               const float* __restrict__ wt2, const float* __restrict__ wt3,
                                               const float* __restrict__ b0, const float* __restrict__ b1,
                                               const float* __restrict__ b2, const float* __restrict__ b3,
                                               float* __restrict__ he1, float* __restrict__ he2,
                                               float* __restrict__ kb, float* __restrict__ vb,
                                               int nmat) {
    __shared__ float lds[64 * LDST];
    int t = threadIdx.x;
    int m = blockIdx.x % nmat, tile = blockIdx.x / nmat;
    float4 scv = reinterpret_cast<const float4*>(scp)[t & 31];
    float4 shv = reinterpret_cast<const float4*>(shp)[t & 31];
    stage64_aff<256>(hraw + (size_t)tile * 64 * CH, lds, t, scv, shv);
    __syncthreads();
    const float* wt = m == 0 ? wt0 : m == 1 ? wt1 : m == 2 ? wt2 : wt3;
    const float* bbp = m == 0 ? b0 : m == 1 ? b1 : m == 2 ? b2 : b3;
    float* dst = m == 0 ? he1 : m == 1 ? he2 : m == 2 ? kb : vb;
    int lane = t & 63;
    int obase = __builtin_amdgcn_readfirstlane((t >> 6) << 5);
    int row = tile * 64 + lane;
    float acc[32];
    #pragma unroll
    for (int k = 0; k < 32; ++k) acc[k] = 0.f;
    rowtile_gemm(lds + lane * LDST, wt, obase, acc);
    #pragma unroll
    for (int k4 = 0; k4 < 8; ++k4) {
        float4 bi4 = ldg4(bbp + obase + k4 * 4);
        float4 o4 = {acc[k4 * 4] + bi4.x, acc[k4 * 4 + 1] + bi4.y,
                     acc[k4 * 4 + 2] + bi4.z, acc[k4 * 4 + 3] + bi4.w};
        *reinterpret_cast<float4*>(&dst[(size_t)row * CH + obase + k4 * 4]) = o4;
    }
}

// Edge transition: de + he -> sigmoid + residual, write raw, accumulate BN stats.
// grid 2500, block 256, 2 tiles of 64 rows each.
__global__ __launch_bounds__(256, 2) void edge_k(const float* __restrict__ dsrc,
                                                 const float* __restrict__ ewsT, const float* __restrict__ eb2,
                                                 const float* __restrict__ he1, const float* __restrict__ he2,
                                                 const float* __restrict__ dscP, const float* __restrict__ dshP,
                                                 float* __restrict__ dout, double* esum, double* esq) {
    __shared__ float lds[64 * LDST];
    int t = threadIdx.x;
    int lane = t & 63;
    int obase = __builtin_amdgcn_readfirstlane((t >> 6) << 5);
    float sl[32], sq[32];
    #pragma unroll
    for (int k = 0; k < 32; ++k) { sl[k] = 0.f; sq[k] = 0.f; }
    for (int tt = 0; tt < 2; ++tt) {
        int tile = blockIdx.x * 2 + tt;
        if (tt) __syncthreads();
        stage64<256>(dsrc + (size_t)tile * 64 * CH, lds, t);
        __syncthreads();
        int row = tile * 64 + lane;
        int bq = row / 10000;
        int rem = row - bq * 10000;
        int iq = rem / 100, jq = rem - iq * 100;
        float acc[32];
        #pragma unroll
        for (int k = 0; k < 32; ++k) acc[k] = 0.f;
        rowtile_gemm(lds + lane * LDST, ewsT, obase, acc);
        const float* h1r = he1 + ((size_t)bq * NN + jq) * CH + obase;
        const float* h2r = he2 + ((size_t)bq * NN + iq) * CH + obase;
        float* orow = dout + (size_t)row * CH + obase;
        #pragma unroll
        for (int k4 = 0; k4 < 8; ++k4) {
            float4 e4 = ldg4(eb2 + obase + k4 * 4);
            float4 h14 = ldg4(h1r + k4 * 4);
            float4 h24 = ldg4(h2r + k4 * 4);
            float4 rw = *reinterpret_cast<const float4*>(&lds[lane * LDST + obase + k4 * 4]);
            float4 sc4 = ldg4(dscP + obase + k4 * 4);
            float4 sh4 = ldg4(dshP + obase + k4 * 4);
            float4 o4;
            float x;
            x = acc[k4 * 4 + 0] + e4.x + h14.x + h24.x;
            o4.x = 1.f / (1.f + __expf(-x)) + rw.x * sc4.x + sh4.x;
            x = acc[k4 * 4 + 1] + e4.y + h14.y + h24.y;
            o4.y = 1.f / (1.f + __expf(-x)) + rw.y * sc4.y + sh4.y;
            x = acc[k4 * 4 + 2] + e4.z + h14.z + h24.z;
            o4.z = 1.f / (1.f + __expf(-x)) + rw.z * sc4.z + sh4.z;
            x = acc[k4 * 4 + 3] + e4.w + h14.w + h24.w;
            o4.w = 1.f / (1.f + __expf(-x)) + rw.w * sc4.w + sh4.w;
            *reinterpret_cast<float4*>(orow + k4 * 4) = o4;
            sl[k4 * 4 + 0] += o4.x; sq[k4 * 4 + 0] += o4.x * o4.x;
            sl[k4 * 4 + 1] += o4.y; sq[k4 * 4 + 1] += o4.y * o4.y;
            sl[k4 * 4 + 2] += o4.z; sq[k4 * 4 + 2] += o4.z * o4.z;
            sl[k4 * 4 + 3] += o4.w; sq[k4 * 4 + 3] += o4.w * o4.w;
        }
    }
    // fold-reduce: pack {sl, sq} into v[64]; at step b each lane keeps the half
    // it will own (bit b of its lane id selects), sends the other half via one
    // shfl_xor, adds. After all steps v[0] on lane l = wave-total of original
    // index l (l<32: sl[l], l>=32: sq[l-32]). All register indices compile-time.
    float v[64];
    #pragma unroll
    for (int k = 0; k < 32; ++k) { v[k] = sl[k]; v[32 + k] = sq[k]; }
    #pragma unroll
    for (int b = 32; b >= 1; b >>= 1) {
        bool up = (lane & b) != 0;
        #pragma unroll
        for (int i = 0; i < b; ++i) {
            float send = up ? v[i] : v[i + b];
            float keep = up ? v[i + b] : v[i];
            v[i] = keep + __shfl_xor(send, b);
        }
    }
    if (lane < 32) atomicAdd(&esum[obase + lane], (double)v[0]);
    else           atomicAdd(&esq[obase + lane - 32], (double)v[0]);
}

// MHA (one block per batch element)
__global__ __launch_bounds__(128) void mha_k(const float* __restrict__ hs_src,
                                             const float* __restrict__ w_in, const float* __restrict__ b_in,
                                             const float* __restrict__ w_out, const float* __restrict__ b_out,
                                             const float* __restrict__ kb, const float* __restrict__ vb,
                                             float* __restrict__ hstmp, double* asum, double* asq,
                                             float* __restrict__ score, int last) {
    __shared__ float hs_s[128], q_s[128], lg[NH * NN], o_s[128];
    int t = threadIdx.x, b = blockIdx.x;
    if (t < 32) reinterpret_cast<float4*>(hs_s)[t] = reinterpret_cast<const float4*>(hs_src + (size_t)b * CH)[t];
    __syncthreads();
    {   // q projection (Wq = rows 0..127 of in_proj)
        const float* wr = w_in + t * CH;
        float a = b_in[t];
        #pragma unroll 8
        for (int c4 = 0; c4 < 32; ++c4) {
            float4 w = ldg4(wr + c4 * 4);
            float4 x = reinterpret_cast<float4*>(hs_s)[c4];
            a += w.x * x.x + w.y * x.y + w.z * x.z + w.w * x.w;
        }
        q_s[t] = a * 0.25f;  // DH^-0.5
    }
    __syncthreads();
    int h = t >> 4, l = t & 15;
    for (int j = l; j < NN; j += 16) {
        const float* kr = kb + ((size_t)b * NN + j) * CH + h * 16;
        float s = 0.f;
        #pragma unroll
        for (int d4 = 0; d4 < 4; ++d4) {
            float4 kv = ldg4(kr + d4 * 4);
            float4 qv = reinterpret_cast<float4*>(q_s)[h * 4 + d4];
            s += kv.x * qv.x + kv.y * qv.y + kv.z * qv.z + kv.w * qv.w;
        }
        lg[h * NN + j] = s;
    }
    float m = -INFINITY;
    for (int j = l; j < NN; j += 16) m = fmaxf(m, lg[h * NN + j]);
    #pragma unroll
    for (int o = 8; o >= 1; o >>= 1) m = fmaxf(m, __shfl_xor(m, o, 16));
    float s = 0.f;
    for (int j = l; j < NN; j += 16) {
        float p = __expf(lg[h * NN + j] - m);
        lg[h * NN + j] = p;
        s += p;
    }
    #pragma unroll
    for (int o = 8; o >= 1; o >>= 1) s += __shfl_xor(s, o, 16);
    float inv = 1.f / s;
    for (int j = l; j < NN; j += 16) lg[h * NN + j] *= inv;
    __syncthreads();
    if (last) {
        if (t < NN) {
            float sc_ = 0.f;
            #pragma unroll
            for (int hh = 0; hh < 8; ++hh) sc_ += lg[hh * NN + t];
            score[(size_t)b * NN + t] = sc_ * 0.125f;
        }
        return;
    }
    {   // o_vec = aw @ v
        int c = t, hc = c >> 4;
        float a = 0.f;
        for (int j = 0; j < NN; ++j) a += lg[hc * NN + j] * vb[((size_t)b * NN + j) * CH + c];
        o_s[c] = a;
    }
    __syncthreads();
    {   // out projection + residual
        const float* wr = w_out + t * CH;
        float a = b_out[t];
        #pragma unroll 8
        for (int c4 = 0; c4 < 32; ++c4) {
            float4 w = ldg4(wr + c4 * 4);
            float4 x = reinterpret_cast<float4*>(o_s)[c4];
            a += w.x * x.x + w.y * x.y + w.z * x.z + w.w * x.w;
        }
        float val = a + hs_s[t];
        hstmp[(size_t)b * CH + t] = val;
        atomicAdd(&asum[t], (double)val);
        atomicAdd(&asq[t], (double)(val * val));
    }
}

__global__ void afin_k(const float* __restrict__ hstmp, const double* __restrict__ asum,
                       const double* __restrict__ asq, const float* __restrict__ gg,
                       const float* __restrict__ bb, float* __restrict__ hss) {
    int c = threadIdx.x;
    double m = asum[c] / 32.0, v = asq[c] / 32.0 - m * m;
    float sc = gg[c] * rsqrtf((float)(v + (double)EPS));
    float sh = bb[c] - (float)m * sc;
    for (int b = 0; b < 32; ++b) hss[b * CH + c] = hstmp[b * CH + c] * sc + sh;
}

// final: materialize normalized dis_mat in place. grid 40000, block 256.
__global__ __launch_bounds__(256) void final_k(const float* __restrict__ dsc,
                                               const float* __restrict__ dsh,
                                               float* __restrict__ dout) {
    size_t idx4 = (size_t)blockIdx.x * 256 + threadIdx.x;  // 10,240,000 float4
    float4 v = reinterpret_cast<float4*>(dout)[idx4];
    int c4 = idx4 & 31;
    float4 sc = reinterpret_cast<const float4*>(dsc)[c4];
    float4 sh = reinterpret_cast<const float4*>(dsh)[c4];
    v.x = v.x * sc.x + sh.x; v.y = v.y * sc.y + sh.y;
    v.z = v.z * sc.z + sh.z; v.w = v.w * sc.w + sh.w;
    reinterpret_cast<float4*>(dout)[idx4] = v;
}

extern "C" void kernel_launch(void* const* d_in, const int* in_sizes, int n_in,
                              void* d_out, int out_size, void* d_ws, size_t ws_size,
                              hipStream_t stream) {
    (void)in_sizes; (void)n_in; (void)out_size; (void)ws_size;
    const float* h_in    = (const float*)d_in[0];
    const int*   adj     = (const int*)d_in[1];
    const float* dis_in  = (const float*)d_in[2];
    const float* hstart  = (const float*)d_in[3];
    const float* gat_W   = (const float*)d_in[4];
    const float* gat_We  = (const float*)d_in[5];
    const float* gat_a   = (const float*)d_in[6];
    const float* et_Ew   = (const float*)d_in[7];
    const float* et_Eb   = (const float*)d_in[8];
    const float* et_Hw1  = (const float*)d_in[9];
    const float* et_Hb1  = (const float*)d_in[10];
    const float* et_Hw2  = (const float*)d_in[11];
    const float* et_Hb2  = (const float*)d_in[12];
    const float* nbn_g   = (const float*)d_in[13];
    const float* nbn_b   = (const float*)d_in[14];
    const float* ebn_g   = (const float*)d_in[15];
    const float* ebn_b   = (const float*)d_in[16];
    const float* abn_g   = (const float*)d_in[17];
    const float* abn_b   = (const float*)d_in[18];
    const float* mha_in_w  = (const float*)d_in[19];
    const float* mha_in_b  = (const float*)d_in[20];
    const float* mha_out_w = (const float*)d_in[21];
    const float* mha_out_b = (const float*)d_in[22];

    float* ws  = (float*)d_ws;
    float* out = (float*)d_out;          // dis raw/final [40960000] + score [3200]

    float* g    = ws + OFF_G;
    float* si   = ws + OFF_SI;
    float* sj   = ws + OFF_SJ;
    float* he1  = ws + OFF_HE1;
    float* he2  = ws + OFF_HE2;
    float* kb   = ws + OFF_KB;
    float* vb   = ws + OFF_VB;
    float* hraw = ws + OFF_HRAW;
    float* hstmp = ws + OFF_HSTMP;
    float* hss  = ws + OFF_HSS;
    float* wes2 = ws + OFF_WES2;
    float* wec  = ws + OFF_WEC;
    float* ewsT = ws + OFF_EWST;
    float* eb2  = ws + OFF_EB2;
    float* wgT  = ws + OFF_WGT;
    float* h1T  = ws + OFF_H1T;
    float* h2T  = ws + OFF_H2T;
    float* wkT  = ws + OFF_WKT;
    float* wvT  = ws + OFF_WVT;
    float* dsc  = ws + OFF_DSC;
    float* dsh  = ws + OFF_DSH;
    double* stats = (double*)(ws + OFF_STATS);   // 2048 doubles
    double* esum = stats + 0;
    double* esq  = stats + 384;
    double* nsum = stats + 768;
    double* nsq  = stats + 1152;
    double* asum = stats + 1536;
    double* asq  = stats + 1792;
    float* nsc  = ws + OFF_NSC;   // 3*128
    float* nsh  = ws + OFF_NSH;   // 3*128

    setup_k<<<16, 128, 0, stream>>>(gat_W, et_Hw1, et_Hw2, mha_in_w, wgT, h1T, h2T, wkT, wvT,
                                    stats, dsc, dsh);

    for (int i = 0; i < NL; ++i) {
        const float* dscP = dsc + i * 128;
        const float* dshP = dsh + i * 128;
        const float* dsrc = (i == 0) ? dis_in : out;
        const float* hsrc = (i == 0) ? h_in : hraw;
        // node-affine of the h-state feeding this layer (identity for i==0 via dsc/dsh slot 0)
        const float* hscP = (i == 0) ? dsc : nsc + (i - 1) * 128;
        const float* hshP = (i == 0) ? dsh : nsh + (i - 1) * 128;
        const float* hssrc = (i == 0) ? hstart : hss;

        fold_k<<<136, 128, 0, stream>>>(gat_We + i * 16384, gat_a + i * 48,
                                        et_Ew + i * 16384, et_Eb + i * 128,
                                        dscP, dshP, wes2, wec, ewsT, eb2);
        p1_k<<<50, 256, 0, stream>>>(hsrc, hscP, hshP, wgT + i * 16384, gat_a + i * 48, g, si, sj);
        att_k<<<3200, 128, 0, stream>>>(dsrc, wes2, wec, si, sj, adj, g, hsrc, hscP, hshP, hraw);
        hstats_k<<<32, 128, 0, stream>>>(hraw, nsum + i * 128, nsq + i * 128);
        bnfin_k<<<1, 128, 0, stream>>>(nsum + i * 128, nsq + i * 128, nbn_g + i * 128, nbn_b + i * 128,
                                       (double)NR, nsc + i * 128, nsh + i * 128);
        int nmat = (i == NL - 1) ? 3 : 4;   // last layer: V projection unused
        p2_k<<<50 * nmat, 256, 0, stream>>>(hraw, nsc + i * 128, nsh + i * 128,
                                            h1T + i * 16384, h2T + i * 16384, wkT + i * 16384, wvT + i * 16384,
                                            et_Hb1 + i * 128, et_Hb2 + i * 128,
                                            mha_in_b + i * 384 + 128, mha_in_b + i * 384 + 256,
                                            he1, he2, kb, vb, nmat);
        edge_k<<<2500, 256, 0, stream>>>(dsrc, ewsT, eb2, he1, he2, dscP, dshP, out,
                                         esum + i * 128, esq + i * 128);
        bnfin_k<<<1, 128, 0, stream>>>(esum + i * 128, esq + i * 128, ebn_g + i * 128, ebn_b + i * 128,
                                       (double)ERR, dsc + (i + 1) * 128, dsh + (i + 1) * 128);
        mha_k<<<32, 128, 0, stream>>>(hssrc, mha_in_w + i * 49152, mha_in_b + i * 384,
                                      mha_out_w + i * 16384, mha_out_b + i * 128,
                                      kb, vb, hstmp, asum + (i < 2 ? i : 0) * 128, asq + (i < 2 ? i : 0) * 128,
                                      out + 40960000, (i == 2) ? 1 : 0);
        if (i < 2)
            afin_k<<<1, 128, 0, stream>>>(hstmp, asum + i * 128, asq + i * 128,
                                          abn_g + i * 128, abn_b + i * 128, hss);
    }
    final_k<<<40000, 256, 0, stream>>>(dsc + 3 * 128, dsh + 3 * 128, out);
}

// Round 6
// 1600.879 us; speedup vs baseline: 1.2553x; 1.2553x over previous
//
#include <hip/hip_runtime.h>
#include <math.h>

// Problem constants
constexpr int BB = 32, NN = 100, CH = 128, NH = 8, NL = 3;
constexpr int NR = BB * NN;          // 3200 node rows
constexpr int ERR = BB * NN * NN;    // 320000 edge rows
constexpr float EPS = 1e-5f;
constexpr int LDST = 132;            // padded LDS row stride (floats) for p1/p2

// ---------------- ws layout (floats) ----------------
constexpr size_t OFF_G     = 0;                       // 409600
constexpr size_t OFF_SI    = OFF_G     + 409600;      // 25600
constexpr size_t OFF_SJ    = OFF_SI    + 25600;       // 25600
constexpr size_t OFF_HE1   = OFF_SJ    + 25600;       // 409600
constexpr size_t OFF_HE2   = OFF_HE1   + 409600;
constexpr size_t OFF_KB    = OFF_HE2   + 409600;
constexpr size_t OFF_VB    = OFF_KB    + 409600;
constexpr size_t OFF_HRAW  = OFF_VB    + 409600;      // raw (pre-BN) h state
constexpr size_t OFF_HSTMP = OFF_HRAW  + 409600;      // 4096
constexpr size_t OFF_HSS   = OFF_HSTMP + 4096;        // 4096
constexpr size_t OFF_WES2  = OFF_HSS   + 4096;        // 1024  (w_es [h][c] * dsc[c])
constexpr size_t OFF_WEC   = OFF_WES2  + 1024;        // 16
constexpr size_t OFF_EWST  = OFF_WEC   + 16;          // 16384 (EwS^T [c][o])
constexpr size_t OFF_EB2   = OFF_EWST  + 16384;       // 128
constexpr size_t OFF_WGT   = OFF_EB2   + 128;         // 3*16384
constexpr size_t OFF_H1T   = OFF_WGT   + 49152;
constexpr size_t OFF_H2T   = OFF_H1T   + 49152;
constexpr size_t OFF_WKT   = OFF_H2T   + 49152;
constexpr size_t OFF_WVT   = OFF_WKT   + 49152;
constexpr size_t OFF_DSC   = OFF_WVT   + 49152;       // 4*128 (dis affine per layer boundary; slot 0 = identity)
constexpr size_t OFF_DSH   = OFF_DSC   + 512;         // 4*128
constexpr size_t OFF_STATS = OFF_DSH   + 512;         // 4096 floats = 2048 DOUBLES (8B aligned)
constexpr size_t OFF_NSC   = OFF_STATS + 4096;        // 3*128 (node BN affine per layer)
constexpr size_t OFF_NSH   = OFF_NSC   + 384;         // 3*128

__device__ __forceinline__ float4 ldg4(const float* p) {
    return *reinterpret_cast<const float4*>(p);
}
__device__ __forceinline__ float get4(const float4& v, int q) {
    return q == 0 ? v.x : q == 1 ? v.y : q == 2 ? v.z : v.w;
}

// stage with per-channel affine applied (c4 = t&31 is thread-constant for NT=256)
template<int NT>
__device__ __forceinline__ void stage64_aff(const float* __restrict__ src, float* lds, int t,
                                            float4 sc, float4 sh) {
    #pragma unroll
    for (int k = 0; k < 2048 / NT; ++k) {
        int idx4 = t + k * NT;
        int row = idx4 >> 5, c = (idx4 & 31) << 2;
        float4 v = ldg4(src + (size_t)idx4 * 4);
        v.x = v.x * sc.x + sh.x; v.y = v.y * sc.y + sh.y;
        v.z = v.z * sc.z + sh.z; v.w = v.w * sc.w + sh.w;
        *reinterpret_cast<float4*>(lds + row * LDST + c) = v;
    }
}

// inner GEMM: one lane's row (in padded LDS) dotted against 32 columns of transposed weight
__device__ __forceinline__ void rowtile_gemm(const float* lds_row, const float* __restrict__ wt,
                                             int obase, float* acc) {
    for (int c = 0; c < CH; c += 4) {
        float4 av = *reinterpret_cast<const float4*>(lds_row + c);
        #pragma unroll
        for (int q = 0; q < 4; ++q) {
            float a = get4(av, q);
            const float* wr = wt + (c + q) * CH + obase;
            #pragma unroll
            for (int k4 = 0; k4 < 8; ++k4) {
                float4 w = ldg4(wr + k4 * 4);
                acc[k4 * 4 + 0] += a * w.x;
                acc[k4 * 4 + 1] += a * w.y;
                acc[k4 * 4 + 2] += a * w.z;
                acc[k4 * 4 + 3] += a * w.w;
            }
        }
    }
}

// ---------------- setup: transpose 15 weight matrices + init block ----------------
// grid 16, block 128. blocks 0..14: sel = bx/3, layer = bx%3. block 15: init stats/affine.
__global__ void setup_k(const float* __restrict__ gat_W, const float* __restrict__ et_Hw1,
                        const float* __restrict__ et_Hw2, const float* __restrict__ mha_in_w,
                        float* __restrict__ wgT, float* __restrict__ h1T, float* __restrict__ h2T,
                        float* __restrict__ wkT, float* __restrict__ wvT,
                        double* stats, float* dsc, float* dsh) {
    int m = blockIdx.x, t = threadIdx.x;
    if (m == 15) {
        #pragma unroll
        for (int k = 0; k < 16; ++k) stats[k * 128 + t] = 0.0;
        dsc[t] = 1.f;  // identity affine for layer-0 dis/h reads
        dsh[t] = 0.f;
        return;
    }
    int layer = m % 3, sel = m / 3;
    const float* src; float* dst;
    if (sel == 0)      { src = gat_W   + layer * 16384;              dst = wgT + layer * 16384; }
    else if (sel == 1) { src = et_Hw1  + layer * 16384;              dst = h1T + layer * 16384; }
    else if (sel == 2) { src = et_Hw2  + layer * 16384;              dst = h2T + layer * 16384; }
    else if (sel == 3) { src = mha_in_w + layer * 49152 + 128 * 128; dst = wkT + layer * 16384; }
    else               { src = mha_in_w + layer * 49152 + 256 * 128; dst = wvT + layer * 16384; }
    for (int o = 0; o < 128; ++o) dst[t * 128 + o] = src[o * 128 + t];
}

// merged fold kernel, grid 136:
//  blocks 0..7:   wes2[h][c] = (sum_d We[h*16+d][c]*a_e[d]) * dscP[c]; wec[h] = sum_c (...)*dshP[c]
//  blocks 8..135: EwS^T[c][o] = Ew[o][c]*dscP[c]; eb2[o] = Eb[o] + sum_c Ew[o][c]*dshP[c]
__global__ void fold_k(const float* __restrict__ We, const float* __restrict__ ga,
                       const float* __restrict__ Ew, const float* __restrict__ Eb,
                       const float* __restrict__ dscP, const float* __restrict__ dshP,
                       float* __restrict__ wes2, float* __restrict__ wec,
                       float* __restrict__ ewsT, float* __restrict__ eb2) {
    __shared__ float red[128];
    int c = threadIdx.x;
    if (blockIdx.x < 8) {
        int h = blockIdx.x;
        float w = 0.f;
        #pragma unroll
        for (int d = 0; d < 16; ++d) w += We[(h * 16 + d) * CH + c] * ga[32 + d];
        wes2[h * CH + c] = w * dscP[c];
        red[c] = w * dshP[c];
        __syncthreads();
        for (int s = 64; s >= 1; s >>= 1) {
            if (c < s) red[c] += red[c + s];
            __syncthreads();
        }
        if (c == 0) wec[h] = red[0];
    } else {
        int o = blockIdx.x - 8;
        float v = Ew[o * CH + c];
        ewsT[c * CH + o] = v * dscP[c];
        red[c] = v * dshP[c];
        __syncthreads();
        for (int s = 64; s >= 1; s >>= 1) {
            if (c < s) red[c] += red[c + s];
            __syncthreads();
        }
        if (c == 0) eb2[o] = Eb[o] + red[0];
    }
}

// ---------------- per-layer kernels ----------------
// P1: g = hn @ W^T; si/sj head dots. grid 50, block 256. hn = hraw*sc+sh applied in staging.
__global__ __launch_bounds__(256, 2) void p1_k(const float* __restrict__ hsrc,
                                               const float* __restrict__ scp, const float* __restrict__ shp,
                                               const float* __restrict__ wgt,
                                               const float* __restrict__ ga,
                                               float* __restrict__ g, float* __restrict__ si,
                                               float* __restrict__ sj) {
    __shared__ float lds[64 * LDST];
    int t = threadIdx.x, tile = blockIdx.x;
    float4 scv = reinterpret_cast<const float4*>(scp)[t & 31];
    float4 shv = reinterpret_cast<const float4*>(shp)[t & 31];
    stage64_aff<256>(hsrc + (size_t)tile * 64 * CH, lds, t, scv, shv);
    __syncthreads();
    int lane = t & 63;
    int obase = __builtin_amdgcn_readfirstlane((t >> 6) << 5);
    int row = tile * 64 + lane;
    float acc[32];
    #pragma unroll
    for (int k = 0; k < 32; ++k) acc[k] = 0.f;
    rowtile_gemm(lds + lane * LDST, wgt, obase, acc);
    float si0 = 0, si1 = 0, sj0 = 0, sj1 = 0;
    #pragma unroll
    for (int k = 0; k < 16; ++k) {
        si0 += acc[k] * ga[k];       sj0 += acc[k] * ga[16 + k];
        si1 += acc[16 + k] * ga[k];  sj1 += acc[16 + k] * ga[16 + k];
    }
    int h0 = obase >> 4;
    si[row * NH + h0] = si0; si[row * NH + h0 + 1] = si1;
    sj[row * NH + h0] = sj0; sj[row * NH + h0 + 1] = sj1;
    #pragma unroll
    for (int k4 = 0; k4 < 8; ++k4) {
        float4 o4 = {acc[k4 * 4], acc[k4 * 4 + 1], acc[k4 * 4 + 2], acc[k4 * 4 + 3]};
        *reinterpret_cast<float4*>(&g[(size_t)row * CH + obase + k4 * 4]) = o4;
    }
}

// GAT attention + h update, with s_e computed in-block from dis rows (b,i,*).
// grid 3200 (b*100+i), block 128. Thread t: h = t&7, jj = t>>3 (16 j-stripes).
__global__ __launch_bounds__(128) void att_k(const float* __restrict__ dsrc,
                                             const float* __restrict__ wes2, const float* __restrict__ wec,
                                             const float* __restrict__ si, const float* __restrict__ sj,
                                             const int* __restrict__ adj, const float* __restrict__ g,
                                             const float* __restrict__ hsrc,
                                             const float* __restrict__ scp, const float* __restrict__ shp,
                                             float* __restrict__ hraw) {
    __shared__ float es[NN * 8];
    int t = threadIdx.x;
    int bi = blockIdx.x;
    int b = bi / NN;
    int h = t & 7, jj = t >> 3;
    // phase A: se[j][h] = dis_raw[b,i,j,:] . wes2[h][:] + wec[h]; then e = leaky(si+sj+se), mask
    float sev[7];
    #pragma unroll
    for (int it = 0; it < 7; ++it) sev[it] = 0.f;
    const float* drow0 = dsrc + (size_t)bi * NN * CH;
    #pragma unroll 8
    for (int c4 = 0; c4 < 32; ++c4) {
        float4 wv = ldg4(wes2 + h * CH + c4 * 4);
        #pragma unroll
        for (int it = 0; it < 7; ++it) {
            int j = jj + it * 16;
            if (j < NN) {
                float4 dv = ldg4(drow0 + (size_t)j * CH + c4 * 4);
                sev[it] += dv.x * wv.x + dv.y * wv.y + dv.z * wv.z + dv.w * wv.w;
            }
        }
    }
    float siv = si[bi * 8 + h];
    float wcv = wec[h];
    #pragma unroll
    for (int it = 0; it < 7; ++it) {
        int j = jj + it * 16;
        if (j < NN) {
            float e = siv + sj[(b * NN + j) * 8 + h] + sev[it] + wcv;
            e = e >= 0.f ? e : 0.2f * e;
            if (adj[(size_t)bi * NN + j] == 0) e = -INFINITY;
            es[j * 8 + h] = e;
        }
    }
    __syncthreads();
    // phase B: softmax over j per (head)
    int hs = t >> 4, l = t & 15;
    float m = -INFINITY;
    for (int j = l; j < NN; j += 16) m = fmaxf(m, es[j * 8 + hs]);
    #pragma unroll
    for (int o = 8; o >= 1; o >>= 1) m = fmaxf(m, __shfl_xor(m, o, 16));
    float s = 0.f;
    for (int j = l; j < NN; j += 16) {
        float p = __expf(es[j * 8 + hs] - m);
        es[j * 8 + hs] = p;
        s += p;
    }
    #pragma unroll
    for (int o = 8; o >= 1; o >>= 1) s += __shfl_xor(s, o, 16);
    float inv = 1.f / s;
    for (int j = l; j < NN; j += 16) es[j * 8 + hs] *= inv;
    __syncthreads();
    // phase C: h_out = att @ g + residual (residual = normalized previous h)
    int c = t, hc = c >> 4;
    float acc = 0.f;
    for (int j = 0; j < NN; ++j) acc += es[j * 8 + hc] * g[((size_t)b * NN + j) * CH + c];
    float res = hsrc[(size_t)bi * CH + c] * scp[c] + shp[c];
    hraw[(size_t)bi * CH + c] = acc + res;
}

__global__ void hstats_k(const float* __restrict__ hraw, double* nsum, double* nsq) {
    int b = blockIdx.x, c = threadIdx.x;
    float s = 0.f, q = 0.f;
    for (int n = 0; n < NN; ++n) {
        float v = hraw[((size_t)b * NN + n) * CH + c];
        s += v; q += v * v;
    }
    atomicAdd(&nsum[c], (double)s);
    atomicAdd(&nsq[c], (double)q);
}

__global__ void bnfin_k(const double* __restrict__ sum, const double* __restrict__ sq,
                        const float* __restrict__ gg, const float* __restrict__ bb,
                        double cnt, float* sc, float* sh) {
    int c = threadIdx.x;
    double m = sum[c] / cnt, v = sq[c] / cnt - m * m;
    float s = gg[c] * rsqrtf((float)(v + (double)EPS));
    sc[c] = s;
    sh[c] = bb[c] - (float)m * s;
}

// P2: he1/he2/k/(v) projections of normalized h. grid 50*nmat, block 256.
__global__ __launch_bounds__(256, 2) void p2_k(const float* __restrict__ hraw,
                                               const float* __restrict__ scp, const float* __restrict__ shp,
                                               const float* __restrict__ wt0, const float* __restrict__ wt1,
                                               const float* __restrict__ wt2, const float* __restrict__ wt3,
                                               const float* __restrict__ b0, const float* __restrict__ b1,
                                               const float* __restrict__ b2, const float* __restrict__ b3,
                                               float* __restrict__ he1, float* __restrict__ he2,
                                               float* __restrict__ kb, float* __restrict__ vb,
                                               int nmat) {
    __shared__ float lds[64 * LDST];
    int t = threadIdx.x;
    int m = blockIdx.x % nmat, tile = blockIdx.x / nmat;
    float4 scv = reinterpret_cast<const float4*>(scp)[t & 31];
    float4 shv = reinterpret_cast<const float4*>(shp)[t & 31];
    stage64_aff<256>(hraw + (size_t)tile * 64 * CH, lds, t, scv, shv);
    __syncthreads();
    const float* wt = m == 0 ? wt0 : m == 1 ? wt1 : m == 2 ? wt2 : wt3;
    const float* bbp = m == 0 ? b0 : m == 1 ? b1 : m == 2 ? b2 : b3;
    float* dst = m == 0 ? he1 : m == 1 ? he2 : m == 2 ? kb : vb;
    int lane = t & 63;
    int obase = __builtin_amdgcn_readfirstlane((t >> 6) << 5);
    int row = tile * 64 + lane;
    float acc[32];
    #pragma unroll
    for (int k = 0; k < 32; ++k) acc[k] = 0.f;
    rowtile_gemm(lds + lane * LDST, wt, obase, acc);
    #pragma unroll
    for (int k4 = 0; k4 < 8; ++k4) {
        float4 bi4 = ldg4(bbp + obase + k4 * 4);
        float4 o4 = {acc[k4 * 4] + bi4.x, acc[k4 * 4 + 1] + bi4.y,
                     acc[k4 * 4 + 2] + bi4.z, acc[k4 * 4 + 3] + bi4.w};
        *reinterpret_cast<float4*>(&dst[(size_t)row * CH + obase + k4 * 4]) = o4;
    }
}

// Edge transition: de + he -> sigmoid + residual, write raw, accumulate BN stats.
// grid 5000 (1 tile of 64 rows per block), block 256, 4 blocks/CU target.
// LDS staged via global_load_lds(16B) with XOR swizzle: logical granule (r, c4)
// lives at lds granule r*32 + (c4 ^ (r&7)); source address pre-swizzled so the
// LDS write is linear (wave-uniform base + lane*16). ds_read applies the same
// XOR -> 2-way bank conflict (free) instead of 16-way.
__global__ __launch_bounds__(256, 4) void edge_k(const float* __restrict__ dsrc,
                                                 const float* __restrict__ ewsT, const float* __restrict__ eb2,
                                                 const float* __restrict__ he1, const float* __restrict__ he2,
                                                 const float* __restrict__ dscP, const float* __restrict__ dshP,
                                                 float* __restrict__ dout, double* esum, double* esq) {
    __shared__ float lds[64 * CH];   // 32 KB, linear
    int t = threadIdx.x;
    int lane = t & 63, w = t >> 6;
    int tile = blockIdx.x;
    const float* src = dsrc + (size_t)tile * 64 * CH;
    #pragma unroll
    for (int it = 0; it < 8; ++it) {
        int gi = it * 256 + w * 64 + lane;        // lds granule this lane fills
        int r = gi >> 5, c4 = gi & 31;
        int c4src = c4 ^ (r & 7);                 // inverse swizzle on the SOURCE
        const float* gp = src + r * CH + c4src * 4;
        float* lp = lds + (size_t)(it * 256 + w * 64) * 4;   // wave-uniform base
        __builtin_amdgcn_global_load_lds((const __attribute__((address_space(1))) void*)gp,
                                         (__attribute__((address_space(3))) void*)lp, 16, 0, 0);
    }
    __syncthreads();

    int obase = __builtin_amdgcn_readfirstlane(w << 5);
    int row = tile * 64 + lane;
    int bq = row / 10000;
    int rem = row - bq * 10000;
    int iq = rem / 100, jq = rem - iq * 100;

    float acc[32];
    #pragma unroll
    for (int k = 0; k < 32; ++k) acc[k] = 0.f;

    const float* lrow = lds + lane * CH;
    int sx = lane & 7;
    for (int c4 = 0; c4 < 32; ++c4) {
        float4 av = *reinterpret_cast<const float4*>(lrow + ((c4 ^ sx) << 2));
        #pragma unroll
        for (int q = 0; q < 4; ++q) {
            float a = get4(av, q);
            const float* wr = ewsT + (c4 * 4 + q) * CH + obase;
            #pragma unroll
            for (int k4 = 0; k4 < 8; ++k4) {
                float4 wv = ldg4(wr + k4 * 4);
                acc[k4 * 4 + 0] += a * wv.x;
                acc[k4 * 4 + 1] += a * wv.y;
                acc[k4 * 4 + 2] += a * wv.z;
                acc[k4 * 4 + 3] += a * wv.w;
            }
        }
    }

    float sl[32], sq[32];
    const float* h1r = he1 + ((size_t)bq * NN + jq) * CH + obase;
    const float* h2r = he2 + ((size_t)bq * NN + iq) * CH + obase;
    float* orow = dout + (size_t)row * CH + obase;
    #pragma unroll
    for (int k4 = 0; k4 < 8; ++k4) {
        float4 e4 = ldg4(eb2 + obase + k4 * 4);
        float4 h14 = ldg4(h1r + k4 * 4);
        float4 h24 = ldg4(h2r + k4 * 4);
        float4 rw = *reinterpret_cast<const float4*>(lrow + (((w * 8 + k4) ^ sx) << 2));
        float4 sc4 = ldg4(dscP + obase + k4 * 4);
        float4 sh4 = ldg4(dshP + obase + k4 * 4);
        float4 o4;
        float x;
        x = acc[k4 * 4 + 0] + e4.x + h14.x + h24.x;
        o4.x = 1.f / (1.f + __expf(-x)) + rw.x * sc4.x + sh4.x;
        x = acc[k4 * 4 + 1] + e4.y + h14.y + h24.y;
        o4.y = 1.f / (1.f + __expf(-x)) + rw.y * sc4.y + sh4.y;
        x = acc[k4 * 4 + 2] + e4.z + h14.z + h24.z;
        o4.z = 1.f / (1.f + __expf(-x)) + rw.z * sc4.z + sh4.z;
        x = acc[k4 * 4 + 3] + e4.w + h14.w + h24.w;
        o4.w = 1.f / (1.f + __expf(-x)) + rw.w * sc4.w + sh4.w;
        *reinterpret_cast<float4*>(orow + k4 * 4) = o4;
        sl[k4 * 4 + 0] = o4.x; sq[k4 * 4 + 0] = o4.x * o4.x;
        sl[k4 * 4 + 1] = o4.y; sq[k4 * 4 + 1] = o4.y * o4.y;
        sl[k4 * 4 + 2] = o4.z; sq[k4 * 4 + 2] = o4.z * o4.z;
        sl[k4 * 4 + 3] = o4.w; sq[k4 * 4 + 3] = o4.w * o4.w;
    }

    // fold-reduce: pack {sl, sq} into v[64]; at step b each lane keeps the half
    // it will own (bit b of its lane id selects), sends the other half via one
    // shfl_xor, adds. After all steps v[0] on lane l = wave-total of original
    // index l (l<32: sl[l], l>=32: sq[l-32]). All register indices compile-time.
    float v[64];
    #pragma unroll
    for (int k = 0; k < 32; ++k) { v[k] = sl[k]; v[32 + k] = sq[k]; }
    #pragma unroll
    for (int b = 32; b >= 1; b >>= 1) {
        bool up = (lane & b) != 0;
        #pragma unroll
        for (int i = 0; i < b; ++i) {
            float send = up ? v[i] : v[i + b];
            float keep = up ? v[i + b] : v[i];
            v[i] = keep + __shfl_xor(send, b);
        }
    }
    if (lane < 32) atomicAdd(&esum[obase + lane], (double)v[0]);
    else           atomicAdd(&esq[obase + lane - 32], (double)v[0]);
}

// MHA (one block per batch element)
__global__ __launch_bounds__(128) void mha_k(const float* __restrict__ hs_src,
                                             const float* __restrict__ w_in, const float* __restrict__ b_in,
                                             const float* __restrict__ w_out, const float* __restrict__ b_out,
                                             const float* __restrict__ kb, const float* __restrict__ vb,
                                             float* __restrict__ hstmp, double* asum, double* asq,
                                             float* __restrict__ score, int last) {
    __shared__ float hs_s[128], q_s[128], lg[NH * NN], o_s[128];
    int t = threadIdx.x, b = blockIdx.x;
    if (t < 32) reinterpret_cast<float4*>(hs_s)[t] = reinterpret_cast<const float4*>(hs_src + (size_t)b * CH)[t];
    __syncthreads();
    {   // q projection (Wq = rows 0..127 of in_proj)
        const float* wr = w_in + t * CH;
        float a = b_in[t];
        #pragma unroll 8
        for (int c4 = 0; c4 < 32; ++c4) {
            float4 w = ldg4(wr + c4 * 4);
            float4 x = reinterpret_cast<float4*>(hs_s)[c4];
            a += w.x * x.x + w.y * x.y + w.z * x.z + w.w * x.w;
        }
        q_s[t] = a * 0.25f;  // DH^-0.5
    }
    __syncthreads();
    int h = t >> 4, l = t & 15;
    for (int j = l; j < NN; j += 16) {
        const float* kr = kb + ((size_t)b * NN + j) * CH + h * 16;
        float s = 0.f;
        #pragma unroll
        for (int d4 = 0; d4 < 4; ++d4) {
            float4 kv = ldg4(kr + d4 * 4);
            float4 qv = reinterpret_cast<float4*>(q_s)[h * 4 + d4];
            s += kv.x * qv.x + kv.y * qv.y + kv.z * qv.z + kv.w * qv.w;
        }
        lg[h * NN + j] = s;
    }
    float m = -INFINITY;
    for (int j = l; j < NN; j += 16) m = fmaxf(m, lg[h * NN + j]);
    #pragma unroll
    for (int o = 8; o >= 1; o >>= 1) m = fmaxf(m, __shfl_xor(m, o, 16));
    float s = 0.f;
    for (int j = l; j < NN; j += 16) {
        float p = __expf(lg[h * NN + j] - m);
        lg[h * NN + j] = p;
        s += p;
    }
    #pragma unroll
    for (int o = 8; o >= 1; o >>= 1) s += __shfl_xor(s, o, 16);
    float inv = 1.f / s;
    for (int j = l; j < NN; j += 16) lg[h * NN + j] *= inv;
    __syncthreads();
    if (last) {
        if (t < NN) {
            float sc_ = 0.f;
            #pragma unroll
            for (int hh = 0; hh < 8; ++hh) sc_ += lg[hh * NN + t];
            score[(size_t)b * NN + t] = sc_ * 0.125f;
        }
        return;
    }
    {   // o_vec = aw @ v
        int c = t, hc = c >> 4;
        float a = 0.f;
        for (int j = 0; j < NN; ++j) a += lg[hc * NN + j] * vb[((size_t)b * NN + j) * CH + c];
        o_s[c] = a;
    }
    __syncthreads();
    {   // out projection + residual
        const float* wr = w_out + t * CH;
        float a = b_out[t];
        #pragma unroll 8
        for (int c4 = 0; c4 < 32; ++c4) {
            float4 w = ldg4(wr + c4 * 4);
            float4 x = reinterpret_cast<float4*>(o_s)[c4];
            a += w.x * x.x + w.y * x.y + w.z * x.z + w.w * x.w;
        }
        float val = a + hs_s[t];
        hstmp[(size_t)b * CH + t] = val;
        atomicAdd(&asum[t], (double)val);
        atomicAdd(&asq[t], (double)(val * val));
    }
}

__global__ void afin_k(const float* __restrict__ hstmp, const double* __restrict__ asum,
                       const double* __restrict__ asq, const float* __restrict__ gg,
                       const float* __restrict__ bb, float* __restrict__ hss) {
    int c = threadIdx.x;
    double m = asum[c] / 32.0, v = asq[c] / 32.0 - m * m;
    float sc = gg[c] * rsqrtf((float)(v + (double)EPS));
    float sh = bb[c] - (float)m * sc;
    for (int b = 0; b < 32; ++b) hss[b * CH + c] = hstmp[b * CH + c] * sc + sh;
}

// final: materialize normalized dis_mat in place. grid 40000, block 256.
__global__ __launch_bounds__(256) void final_k(const float* __restrict__ dsc,
                                               const float* __restrict__ dsh,
                                               float* __restrict__ dout) {
    size_t idx4 = (size_t)blockIdx.x * 256 + threadIdx.x;  // 10,240,000 float4
    float4 v = reinterpret_cast<float4*>(dout)[idx4];
    int c4 = idx4 & 31;
    float4 sc = reinterpret_cast<const float4*>(dsc)[c4];
    float4 sh = reinterpret_cast<const float4*>(dsh)[c4];
    v.x = v.x * sc.x + sh.x; v.y = v.y * sc.y + sh.y;
    v.z = v.z * sc.z + sh.z; v.w = v.w * sc.w + sh.w;
    reinterpret_cast<float4*>(dout)[idx4] = v;
}

extern "C" void kernel_launch(void* const* d_in, const int* in_sizes, int n_in,
                              void* d_out, int out_size, void* d_ws, size_t ws_size,
                              hipStream_t stream) {
    (void)in_sizes; (void)n_in; (void)out_size; (void)ws_size;
    const float* h_in    = (const float*)d_in[0];
    const int*   adj     = (const int*)d_in[1];
    const float* dis_in  = (const float*)d_in[2];
    const float* hstart  = (const float*)d_in[3];
    const float* gat_W   = (const float*)d_in[4];
    const float* gat_We  = (const float*)d_in[5];
    const float* gat_a   = (const float*)d_in[6];
    const float* et_Ew   = (const float*)d_in[7];
    const float* et_Eb   = (const float*)d_in[8];
    const float* et_Hw1  = (const float*)d_in[9];
    const float* et_Hb1  = (const float*)d_in[10];
    const float* et_Hw2  = (const float*)d_in[11];
    const float* et_Hb2  = (const float*)d_in[12];
    const float* nbn_g   = (const float*)d_in[13];
    const float* nbn_b   = (const float*)d_in[14];
    const float* ebn_g   = (const float*)d_in[15];
    const float* ebn_b   = (const float*)d_in[16];
    const float* abn_g   = (const float*)d_in[17];
    const float* abn_b   = (const float*)d_in[18];
    const float* mha_in_w  = (const float*)d_in[19];
    const float* mha_in_b  = (const float*)d_in[20];
    const float* mha_out_w = (const float*)d_in[21];
    const float* mha_out_b = (const float*)d_in[22];

    float* ws  = (float*)d_ws;
    float* out = (float*)d_out;          // dis raw/final [40960000] + score [3200]

    float* g    = ws + OFF_G;
    float* si   = ws + OFF_SI;
    float* sj   = ws + OFF_SJ;
    float* he1  = ws + OFF_HE1;
    float* he2  = ws + OFF_HE2;
    float* kb   = ws + OFF_KB;
    float* vb   = ws + OFF_VB;
    float* hraw = ws + OFF_HRAW;
    float* hstmp = ws + OFF_HSTMP;
    float* hss  = ws + OFF_HSS;
    float* wes2 = ws + OFF_WES2;
    float* wec  = ws + OFF_WEC;
    float* ewsT = ws + OFF_EWST;
    float* eb2  = ws + OFF_EB2;
    float* wgT  = ws + OFF_WGT;
    float* h1T  = ws + OFF_H1T;
    float* h2T  = ws + OFF_H2T;
    float* wkT  = ws + OFF_WKT;
    float* wvT  = ws + OFF_WVT;
    float* dsc  = ws + OFF_DSC;
    float* dsh  = ws + OFF_DSH;
    double* stats = (double*)(ws + OFF_STATS);   // 2048 doubles
    double* esum = stats + 0;
    double* esq  = stats + 384;
    double* nsum = stats + 768;
    double* nsq  = stats + 1152;
    double* asum = stats + 1536;
    double* asq  = stats + 1792;
    float* nsc  = ws + OFF_NSC;   // 3*128
    float* nsh  = ws + OFF_NSH;   // 3*128

    setup_k<<<16, 128, 0, stream>>>(gat_W, et_Hw1, et_Hw2, mha_in_w, wgT, h1T, h2T, wkT, wvT,
                                    stats, dsc, dsh);

    for (int i = 0; i < NL; ++i) {
        const float* dscP = dsc + i * 128;
        const float* dshP = dsh + i * 128;
        const float* dsrc = (i == 0) ? dis_in : out;
        const float* hsrc = (i == 0) ? h_in : hraw;
        // node-affine of the h-state feeding this layer (identity for i==0 via dsc/dsh slot 0)
        const float* hscP = (i == 0) ? dsc : nsc + (i - 1) * 128;
        const float* hshP = (i == 0) ? dsh : nsh + (i - 1) * 128;
        const float* hssrc = (i == 0) ? hstart : hss;

        fold_k<<<136, 128, 0, stream>>>(gat_We + i * 16384, gat_a + i * 48,
                                        et_Ew + i * 16384, et_Eb + i * 128,
                                        dscP, dshP, wes2, wec, ewsT, eb2);
        p1_k<<<50, 256, 0, stream>>>(hsrc, hscP, hshP, wgT + i * 16384, gat_a + i * 48, g, si, sj);
        att_k<<<3200, 128, 0, stream>>>(dsrc, wes2, wec, si, sj, adj, g, hsrc, hscP, hshP, hraw);
        hstats_k<<<32, 128, 0, stream>>>(hraw, nsum + i * 128, nsq + i * 128);
        bnfin_k<<<1, 128, 0, stream>>>(nsum + i * 128, nsq + i * 128, nbn_g + i * 128, nbn_b + i * 128,
                                       (double)NR, nsc + i * 128, nsh + i * 128);
        int nmat = (i == NL - 1) ? 3 : 4;   // last layer: V projection unused
        p2_k<<<50 * nmat, 256, 0, stream>>>(hraw, nsc + i * 128, nsh + i * 128,
                                            h1T + i * 16384, h2T + i * 16384, wkT + i * 16384, wvT + i * 16384,
                                            et_Hb1 + i * 128, et_Hb2 + i * 128,
                                            mha_in_b + i * 384 + 128, mha_in_b + i * 384 + 256,
                                            he1, he2, kb, vb, nmat);
        edge_k<<<5000, 256, 0, stream>>>(dsrc, ewsT, eb2, he1, he2, dscP, dshP, out,
                                         esum + i * 128, esq + i * 128);
        bnfin_k<<<1, 128, 0, stream>>>(esum + i * 128, esq + i * 128, ebn_g + i * 128, ebn_b + i * 128,
                                       (double)ERR, dsc + (i + 1) * 128, dsh + (i + 1) * 128);
        mha_k<<<32, 128, 0, stream>>>(hssrc, mha_in_w + i * 49152, mha_in_b + i * 384,
                                      mha_out_w + i * 16384, mha_out_b + i * 128,
                                      kb, vb, hstmp, asum + (i < 2 ? i : 0) * 128, asq + (i < 2 ? i : 0) * 128,
                                      out + 40960000, (i == 2) ? 1 : 0);
        if (i < 2)
            afin_k<<<1, 128, 0, stream>>>(hstmp, asum + i * 128, asq + i * 128,
                                          abn_g + i * 128, abn_b + i * 128, hss);
    }
    final_k<<<40000, 256, 0, stream>>>(dsc + 3 * 128, dsh + 3 * 128, out);
}